// Round 1
// baseline (35696.771 us; speedup 1.0000x reference)
//
#include <hip/hip_runtime.h>

#define BB   64
#define TDEC 400
#define TENC 512
#define DD   256
#define PRE  128
#define NOUT 400
#define G3   768   // 3*DD

// ---------- fast device math (fp32, well within 1e-2 absmax budget) ----------
__device__ __forceinline__ float fast_sigmoid(float x) {
    return 1.0f / (1.0f + __expf(-x));
}
__device__ __forceinline__ float fast_tanh(float x) {
    float xc = fminf(9.0f, fmaxf(-9.0f, x));   // tanh(9) == 1 to fp32
    float t  = __expf(2.0f * xc);
    return (t - 1.0f) / (t + 1.0f);
}

// ---------- prenet: p = relu(relu(x@W1+b1)@W2+b2), 8 rows per block ----------
__global__ __launch_bounds__(256) void prenet_kernel(
    const float* __restrict__ x, const float* __restrict__ W1, const float* __restrict__ b1,
    const float* __restrict__ W2, const float* __restrict__ b2, float* __restrict__ p)
{
    __shared__ __align__(16) float xs[8][NOUT];
    __shared__ __align__(16) float hs[8][DD];
    const int row0 = blockIdx.x * 8;
    const int tid = threadIdx.x;
    for (int idx = tid; idx < 8 * NOUT; idx += 256) {
        int m = idx / NOUT, i = idx - m * NOUT;
        xs[m][i] = x[(size_t)(row0 + m) * NOUT + i];
    }
    __syncthreads();
    {
        const int j = tid;  // 256 threads = DD outputs
        float acc[8];
        float bj = b1[j];
        #pragma unroll
        for (int m = 0; m < 8; m++) acc[m] = bj;
        #pragma unroll 4
        for (int i = 0; i < NOUT; i++) {
            float w = W1[i * DD + j];
            #pragma unroll
            for (int m = 0; m < 8; m++) acc[m] = fmaf(xs[m][i], w, acc[m]);
        }
        #pragma unroll
        for (int m = 0; m < 8; m++) hs[m][j] = fmaxf(acc[m], 0.0f);
    }
    __syncthreads();
    if (tid < PRE) {
        const int j = tid;
        float acc[8];
        float bj = b2[j];
        #pragma unroll
        for (int m = 0; m < 8; m++) acc[m] = bj;
        #pragma unroll 4
        for (int i = 0; i < DD; i++) {
            float w = W2[i * PRE + j];
            #pragma unroll
            for (int m = 0; m < 8; m++) acc[m] = fmaf(hs[m][i], w, acc[m]);
        }
        #pragma unroll
        for (int m = 0; m < 8; m++) p[(size_t)(row0 + m) * PRE + j] = fmaxf(acc[m], 0.0f);
    }
}

// ---------- keys = memory @ Wm, 8 rows per block ----------
__global__ __launch_bounds__(256) void keys_kernel(
    const float* __restrict__ mem, const float* __restrict__ Wm, float* __restrict__ keys)
{
    __shared__ __align__(16) float xs[8][DD];
    const int row0 = blockIdx.x * 8;
    const int tid = threadIdx.x;
    for (int idx = tid; idx < 8 * DD; idx += 256) {
        int m = idx >> 8, i = idx & 255;
        xs[m][i] = mem[(size_t)(row0 + m) * DD + i];
    }
    __syncthreads();
    const int j = tid;
    float acc[8] = {0.f,0.f,0.f,0.f,0.f,0.f,0.f,0.f};
    #pragma unroll 4
    for (int i = 0; i < DD; i++) {
        float w = Wm[i * DD + j];
        #pragma unroll
        for (int m = 0; m < 8; m++) acc[m] = fmaf(xs[m][i], w, acc[m]);
    }
    #pragma unroll
    for (int m = 0; m < 8; m++) keys[(size_t)(row0 + m) * DD + j] = acc[m];
}

// ---------- y = attn_hist @ Wo + bo, 8 rows per block ----------
__global__ __launch_bounds__(448) void out_kernel(
    const float* __restrict__ ah, const float* __restrict__ Wo, const float* __restrict__ bo,
    float* __restrict__ y)
{
    __shared__ __align__(16) float xs[8][DD];
    const int row0 = blockIdx.x * 8;
    const int tid = threadIdx.x;
    for (int idx = tid; idx < 8 * DD; idx += 448) {
        int m = idx >> 8, i = idx & 255;
        xs[m][i] = ah[(size_t)(row0 + m) * DD + i];
    }
    __syncthreads();
    if (tid < NOUT) {
        const int j = tid;
        float acc[8];
        float bj = bo[j];
        #pragma unroll
        for (int m = 0; m < 8; m++) acc[m] = bj;
        #pragma unroll 4
        for (int i = 0; i < DD; i++) {
            float w = Wo[i * NOUT + j];
            #pragma unroll
            for (int m = 0; m < 8; m++) acc[m] = fmaf(xs[m][i], w, acc[m]);
        }
        #pragma unroll
        for (int m = 0; m < 8; m++) y[(size_t)(row0 + m) * NOUT + j] = acc[m];
    }
}

// ---------- persistent per-batch-element decoder: 400 sequential steps ----------
__global__ __launch_bounds__(768) void decoder_kernel(
    const float* __restrict__ p, const float* __restrict__ keys, const float* __restrict__ mem,
    const float* __restrict__ k0, const float* __restrict__ r0,
    const float* __restrict__ bi0, const float* __restrict__ br0,
    const float* __restrict__ k1, const float* __restrict__ r1,
    const float* __restrict__ bi1, const float* __restrict__ br1,
    const float* __restrict__ Wq, const float* __restrict__ v,
    const float* __restrict__ Wa, float* __restrict__ ahist)
{
    __shared__ __align__(16) float cin[PRE + DD];   // [prenet_t | att_{t-1}]
    __shared__ __align__(16) float h0[DD], h1[DD];
    __shared__ __align__(16) float gx[G3], gh[G3];
    __shared__ __align__(16) float hc[2 * DD];      // [h1n | ctx]
    __shared__ __align__(16) float qv[DD];
    __shared__ __align__(16) float sc[TENC];        // score, then unnormalized alpha
    __shared__ __align__(16) float vs[DD];
    __shared__ __align__(16) float bi0s[G3], br0s[G3], bi1s[G3], br1s[G3];
    __shared__ float redm[12], reds[12];

    const int tid = threadIdx.x;
    const int b = blockIdx.x;
    for (int i = tid; i < G3; i += 768) {
        bi0s[i] = bi0[i]; br0s[i] = br0[i]; bi1s[i] = bi1[i]; br1s[i] = br1[i];
    }
    if (tid < DD) { vs[tid] = v[tid]; h0[tid] = 0.0f; h1[tid] = 0.0f; cin[PRE + tid] = 0.0f; }
    __syncthreads();

    const float* keyb = keys + (size_t)b * TENC * DD;
    const float* memb = mem  + (size_t)b * TENC * DD;

    #pragma unroll 1
    for (int t = 0; t < TDEC; t++) {
        if (tid < PRE) cin[tid] = p[((size_t)b * TDEC + t) * PRE + tid];
        __syncthreads();

        // ---- GRU0 gate matmuls: gx = cin@k0 + bi0 ; gh = h0@r0 + br0 ----
        {
            const int j = tid;
            const float4* c4 = (const float4*)cin;
            float a0 = bi0s[j], a1 = 0.f, a2 = 0.f, a3 = 0.f;
            #pragma unroll 4
            for (int i = 0; i < (PRE + DD) / 4; i++) {
                float4 c = c4[i];
                const float* kk = k0 + (size_t)(i * 4) * G3 + j;
                a0 = fmaf(c.x, kk[0],      a0);
                a1 = fmaf(c.y, kk[G3],     a1);
                a2 = fmaf(c.z, kk[2 * G3], a2);
                a3 = fmaf(c.w, kk[3 * G3], a3);
            }
            float gxv = (a0 + a1) + (a2 + a3);
            const float4* h4 = (const float4*)h0;
            float e0 = br0s[j], e1 = 0.f, e2 = 0.f, e3 = 0.f;
            #pragma unroll 4
            for (int i = 0; i < DD / 4; i++) {
                float4 hv = h4[i];
                const float* rr = r0 + (size_t)(i * 4) * G3 + j;
                e0 = fmaf(hv.x, rr[0],      e0);
                e1 = fmaf(hv.y, rr[G3],     e1);
                e2 = fmaf(hv.z, rr[2 * G3], e2);
                e3 = fmaf(hv.w, rr[3 * G3], e3);
            }
            gx[j] = gxv; gh[j] = (e0 + e1) + (e2 + e3);
        }
        __syncthreads();
        if (tid < DD) {   // GRU0 combine (Keras reset_after)
            const int d = tid;
            float z = fast_sigmoid(gx[d] + gh[d]);
            float r = fast_sigmoid(gx[DD + d] + gh[DD + d]);
            float hcand = fast_tanh(gx[2 * DD + d] + r * gh[2 * DD + d]);
            h0[d] = z * h0[d] + (1.0f - z) * hcand;
        }
        __syncthreads();

        // ---- GRU1 gate matmuls: gx = h0n@k1 + bi1 ; gh = h1@r1 + br1 ----
        {
            const int j = tid;
            const float4* x4 = (const float4*)h0;
            float a0 = bi1s[j], a1 = 0.f, a2 = 0.f, a3 = 0.f;
            #pragma unroll 4
            for (int i = 0; i < DD / 4; i++) {
                float4 c = x4[i];
                const float* kk = k1 + (size_t)(i * 4) * G3 + j;
                a0 = fmaf(c.x, kk[0],      a0);
                a1 = fmaf(c.y, kk[G3],     a1);
                a2 = fmaf(c.z, kk[2 * G3], a2);
                a3 = fmaf(c.w, kk[3 * G3], a3);
            }
            float gxv = (a0 + a1) + (a2 + a3);
            const float4* h4 = (const float4*)h1;
            float e0 = br1s[j], e1 = 0.f, e2 = 0.f, e3 = 0.f;
            #pragma unroll 4
            for (int i = 0; i < DD / 4; i++) {
                float4 hv = h4[i];
                const float* rr = r1 + (size_t)(i * 4) * G3 + j;
                e0 = fmaf(hv.x, rr[0],      e0);
                e1 = fmaf(hv.y, rr[G3],     e1);
                e2 = fmaf(hv.z, rr[2 * G3], e2);
                e3 = fmaf(hv.w, rr[3 * G3], e3);
            }
            gx[j] = gxv; gh[j] = (e0 + e1) + (e2 + e3);
        }
        __syncthreads();
        if (tid < DD) {   // GRU1 combine -> h1n
            const int d = tid;
            float z = fast_sigmoid(gx[d] + gh[d]);
            float r = fast_sigmoid(gx[DD + d] + gh[DD + d]);
            float hcand = fast_tanh(gx[2 * DD + d] + r * gh[2 * DD + d]);
            float hn = z * h1[d] + (1.0f - z) * hcand;
            h1[d] = hn; hc[d] = hn;
        }
        __syncthreads();

        // ---- q = h1n @ Wq ----
        if (tid < DD) {
            const int d = tid;
            const float4* h4 = (const float4*)h1;
            float a0 = 0.f, a1 = 0.f, a2 = 0.f, a3 = 0.f;
            #pragma unroll 4
            for (int i = 0; i < DD / 4; i++) {
                float4 hv = h4[i];
                const float* ww = Wq + (size_t)(i * 4) * DD + d;
                a0 = fmaf(hv.x, ww[0],      a0);
                a1 = fmaf(hv.y, ww[DD],     a1);
                a2 = fmaf(hv.z, ww[2 * DD], a2);
                a3 = fmaf(hv.w, ww[3 * DD], a3);
            }
            qv[d] = (a0 + a1) + (a2 + a3);
        }
        __syncthreads();

        // ---- score[e] = v . tanh(keys[e] + q) ----
        float smax = -3.0e38f;
        if (tid < TENC) {
            const float4* kr = (const float4*)(keyb + (size_t)tid * DD);
            const float4* q4 = (const float4*)qv;
            const float4* v4 = (const float4*)vs;
            float s0 = 0.f, s1 = 0.f, s2 = 0.f, s3 = 0.f;
            #pragma unroll 4
            for (int i = 0; i < DD / 4; i++) {
                float4 kk = kr[i]; float4 qq = q4[i]; float4 vv = v4[i];
                s0 = fmaf(fast_tanh(kk.x + qq.x), vv.x, s0);
                s1 = fmaf(fast_tanh(kk.y + qq.y), vv.y, s1);
                s2 = fmaf(fast_tanh(kk.z + qq.z), vv.z, s2);
                s3 = fmaf(fast_tanh(kk.w + qq.w), vv.w, s3);
            }
            float s = (s0 + s1) + (s2 + s3);
            sc[tid] = s;
            smax = s;
        }
        // block max reduce (all 768 threads participate; wave=64)
        #pragma unroll
        for (int off = 32; off > 0; off >>= 1) smax = fmaxf(smax, __shfl_down(smax, off));
        if ((tid & 63) == 0) redm[tid >> 6] = smax;
        __syncthreads();
        if (tid == 0) {
            float mm = redm[0];
            for (int i = 1; i < 12; i++) mm = fmaxf(mm, redm[i]);
            redm[0] = mm;
        }
        __syncthreads();
        const float m = redm[0];
        float aexp = 0.0f;
        if (tid < TENC) { aexp = __expf(sc[tid] - m); sc[tid] = aexp; }
        #pragma unroll
        for (int off = 32; off > 0; off >>= 1) aexp += __shfl_down(aexp, off);
        if ((tid & 63) == 0) reds[tid >> 6] = aexp;
        __syncthreads();
        if (tid == 0) {
            float ss = 0.f;
            for (int i = 0; i < 12; i++) ss += reds[i];
            reds[0] = ss;
        }
        __syncthreads();
        const float invS = 1.0f / reds[0];

        // ---- ctx = (alpha @ memory) / S ----
        if (tid < DD) {
            const int d = tid;
            float c0 = 0.f, c1 = 0.f, c2 = 0.f, c3 = 0.f;
            #pragma unroll 4
            for (int e = 0; e < TENC; e += 4) {
                c0 = fmaf(sc[e],     memb[(size_t)e * DD + d],       c0);
                c1 = fmaf(sc[e + 1], memb[(size_t)(e + 1) * DD + d], c1);
                c2 = fmaf(sc[e + 2], memb[(size_t)(e + 2) * DD + d], c2);
                c3 = fmaf(sc[e + 3], memb[(size_t)(e + 3) * DD + d], c3);
            }
            hc[DD + d] = ((c0 + c1) + (c2 + c3)) * invS;
        }
        __syncthreads();

        // ---- attn = [h1n | ctx] @ Wa ; carry + log to history ----
        if (tid < DD) {
            const int d = tid;
            const float4* x4 = (const float4*)hc;
            float a0 = 0.f, a1 = 0.f, a2 = 0.f, a3 = 0.f;
            #pragma unroll 4
            for (int i = 0; i < (2 * DD) / 4; i++) {
                float4 xv = x4[i];
                const float* ww = Wa + (size_t)(i * 4) * DD + d;
                a0 = fmaf(xv.x, ww[0],      a0);
                a1 = fmaf(xv.y, ww[DD],     a1);
                a2 = fmaf(xv.z, ww[2 * DD], a2);
                a3 = fmaf(xv.w, ww[3 * DD], a3);
            }
            float at = (a0 + a1) + (a2 + a3);
            cin[PRE + d] = at;
            ahist[((size_t)b * TDEC + t) * DD + d] = at;
        }
        __syncthreads();
    }
}

extern "C" void kernel_launch(void* const* d_in, const int* in_sizes, int n_in,
                              void* d_out, int out_size, void* d_ws, size_t ws_size,
                              hipStream_t stream)
{
    const float* dec    = (const float*)d_in[0];
    const float* memory = (const float*)d_in[1];
    const float* W1  = (const float*)d_in[2];
    const float* b1  = (const float*)d_in[3];
    const float* W2  = (const float*)d_in[4];
    const float* b2  = (const float*)d_in[5];
    const float* k0  = (const float*)d_in[6];
    const float* r0  = (const float*)d_in[7];
    const float* bi0 = (const float*)d_in[8];
    const float* br0 = (const float*)d_in[9];
    const float* k1  = (const float*)d_in[10];
    const float* r1  = (const float*)d_in[11];
    const float* bi1 = (const float*)d_in[12];
    const float* br1 = (const float*)d_in[13];
    const float* Wq  = (const float*)d_in[14];
    const float* Wm  = (const float*)d_in[15];
    const float* v   = (const float*)d_in[16];
    const float* Wa  = (const float*)d_in[17];
    const float* Wo  = (const float*)d_in[18];
    const float* bo  = (const float*)d_in[19];
    float* out = (float*)d_out;

    // workspace layout (fp32): p | keys | attn_hist  = 72.9 MB
    float* ws    = (float*)d_ws;
    float* p     = ws;                                  // B*TDEC*PRE
    float* keys  = p    + (size_t)BB * TDEC * PRE;      // B*TENC*DD
    float* ahist = keys + (size_t)BB * TENC * DD;       // B*TDEC*DD

    prenet_kernel<<<BB * TDEC / 8, 256, 0, stream>>>(dec, W1, b1, W2, b2, p);
    keys_kernel<<<BB * TENC / 8, 256, 0, stream>>>(memory, Wm, keys);
    decoder_kernel<<<BB, 768, 0, stream>>>(p, keys, memory, k0, r0, bi0, br0,
                                           k1, r1, bi1, br1, Wq, v, Wa, ahist);
    out_kernel<<<BB * TDEC / 8, 448, 0, stream>>>(ahist, Wo, bo, out);
}